// Round 1
// baseline (394.938 us; speedup 1.0000x reference)
//
#include <hip/hip_runtime.h>
#include <stdint.h>

#define NR 8192
#define FD 256

typedef __attribute__((ext_vector_type(8))) short bf16x8;
typedef __attribute__((ext_vector_type(4))) float f32x4;

__device__ __forceinline__ float leaky_f(float z){ return z >= 0.0f ? z : 0.1f * z; }

__device__ __forceinline__ unsigned short f2bf(float f){
    union { float f; uint32_t u; } v; v.f = f;
    uint32_t r = v.u + 0x7fffu + ((v.u >> 16) & 1u);
    return (unsigned short)(r >> 16);
}
__device__ __forceinline__ float bf2f(unsigned short h){
    union { uint32_t u; float f; } v; v.u = ((uint32_t)h) << 16;
    return v.f;
}

// ---------------------------------------------------------------------------
// k0: precompute bf16 hi/lo split of a weight matrix (removes per-tile
// conversion VALU from the GEMM inner loop; weights re-read ~128x from L2)
__global__ void k0_prep(const float* __restrict__ W, short* __restrict__ hi,
                        short* __restrict__ lo, int n){
    int i = blockIdx.x * 256 + threadIdx.x;
    if (i < n){
        float v = W[i];
        unsigned short h = f2bf(v);
        hi[i] = (short)h;
        lo[i] = (short)f2bf(v - bf2f(h));
    }
}

// ---------------------------------------------------------------------------
// k1: s = x@Wa, t = x@Wb  (Wa=W3[:256], Wb=W3[256:]). One wave per row.
__global__ __launch_bounds__(256) void k1_st(const float* __restrict__ x,
                                             const float* __restrict__ W3,
                                             float* __restrict__ s,
                                             float* __restrict__ t){
    int wave = threadIdx.x >> 6;
    int lane = threadIdx.x & 63;
    int row  = blockIdx.x * 4 + wave;
    const float* xr = x + (size_t)row * FD;
    float as = 0.0f, at = 0.0f;
    #pragma unroll
    for (int m = 0; m < 4; ++m){
        int kk = lane + 64 * m;
        float xv = xr[kk];
        as += xv * W3[kk];
        at += xv * W3[FD + kk];
    }
    #pragma unroll
    for (int off = 32; off > 0; off >>= 1){
        as += __shfl_xor(as, off, 64);
        at += __shfl_xor(at, off, 64);
    }
    if (lane == 0){ s[row] = as; t[row] = at; }
}

// ---------------------------------------------------------------------------
// k3: counting-rank of t (ascending, index tie-break -> permutation).
// rank[j] = position of t_j in sorted order; ts = sorted t values.
__global__ __launch_bounds__(256) void k3_rank(const float* __restrict__ t,
                                               float* __restrict__ ts,
                                               int* __restrict__ rank){
    __shared__ __align__(16) float lt[NR];
    for (int i = threadIdx.x; i < NR; i += 256) lt[i] = t[i];
    __syncthreads();
    int j = blockIdx.x * 256 + threadIdx.x;
    float tj = lt[j];
    int cnt = 0;
    for (int jp = 0; jp < NR; jp += 4){
        float4 v = *reinterpret_cast<const float4*>(&lt[jp]);
        cnt += (v.x < tj) || (v.x == tj && (jp + 0) < j);
        cnt += (v.y < tj) || (v.y == tj && (jp + 1) < j);
        cnt += (v.z < tj) || (v.z == tj && (jp + 2) < j);
        cnt += (v.w < tj) || (v.w == tj && (jp + 3) < j);
    }
    rank[j] = cnt;
    ts[cnt] = tj;
}

// ---------------------------------------------------------------------------
// gemm_nt: out[i][n] = leaky( sum_k A[i][k]*Wt[n][k] + bias[n] ) (+ addend)
// Split-bf16 MFMA (a_hi*b_hi + a_lo*b_hi + a_hi*b_lo) for ~f32 accuracy.
// SCATTER: rows written to out[perm[i]] (fuses sort-gather for Gs).
// Tile: block = 4 waves x 16 rows = 64 rows, 128 cols; grid (128, 2).
template<bool SCATTER, bool ADD>
__global__ __launch_bounds__(256) void gemm_nt(
    const float* __restrict__ A,
    const short* __restrict__ Whi, const short* __restrict__ Wlo,
    const float* __restrict__ bias,
    const float* __restrict__ addend,
    const int* __restrict__ perm,
    float* __restrict__ out)
{
    int wave = threadIdx.x >> 6;
    int lane = threadIdx.x & 63;
    int rowBase = blockIdx.x * 64 + wave * 16;
    int colBase = blockIdx.y * 128;
    int m16 = lane & 15;
    int k8  = (lane >> 4) * 8;

    f32x4 acc[8];
    #pragma unroll
    for (int c = 0; c < 8; ++c) acc[c] = (f32x4){0.f, 0.f, 0.f, 0.f};

    const float* arow = A + (size_t)(rowBase + m16) * FD + k8;

    #pragma unroll
    for (int ks = 0; ks < 8; ++ks){
        int kb = ks * 32;
        float4 a0 = *reinterpret_cast<const float4*>(arow + kb);
        float4 a1 = *reinterpret_cast<const float4*>(arow + kb + 4);
        float a8[8] = {a0.x, a0.y, a0.z, a0.w, a1.x, a1.y, a1.z, a1.w};
        bf16x8 ahi, alo;
        #pragma unroll
        for (int e = 0; e < 8; ++e){
            unsigned short h = f2bf(a8[e]);
            ahi[e] = (short)h;
            alo[e] = (short)f2bf(a8[e] - bf2f(h));
        }
        #pragma unroll
        for (int c = 0; c < 8; ++c){
            size_t boff = (size_t)(colBase + c * 16 + m16) * FD + k8 + kb;
            bf16x8 bhi = *reinterpret_cast<const bf16x8*>(Whi + boff);
            bf16x8 blo = *reinterpret_cast<const bf16x8*>(Wlo + boff);
            acc[c] = __builtin_amdgcn_mfma_f32_16x16x32_bf16(ahi, bhi, acc[c], 0, 0, 0);
            acc[c] = __builtin_amdgcn_mfma_f32_16x16x32_bf16(alo, bhi, acc[c], 0, 0, 0);
            acc[c] = __builtin_amdgcn_mfma_f32_16x16x32_bf16(ahi, blo, acc[c], 0, 0, 0);
        }
    }

    int rq = (lane >> 4) * 4;
    #pragma unroll
    for (int c = 0; c < 8; ++c){
        int gcol = colBase + c * 16 + m16;
        float bs = bias[gcol];
        #pragma unroll
        for (int j = 0; j < 4; ++j){
            int grow = rowBase + rq + j;
            float v = leaky_f(acc[c][j] + bs);
            if (ADD) v += addend[(size_t)grow * FD + gcol];
            int orow = SCATTER ? perm[grow] : grow;
            out[(size_t)orow * FD + gcol] = v;
        }
    }
}

// ---------------------------------------------------------------------------
// k4a: per-chunk (32 rows) column sums of Gs and ts*Gs
__global__ __launch_bounds__(256) void k4a_partial(const float* __restrict__ Gs,
                                                   const float* __restrict__ ts,
                                                   float* __restrict__ p0,
                                                   float* __restrict__ p1){
    int col = threadIdx.x;
    int chunk = blockIdx.x;
    int base = chunk * 32;
    float s0 = 0.f, s1 = 0.f;
    #pragma unroll
    for (int r = 0; r < 32; ++r){
        float g = Gs[(size_t)(base + r) * FD + col];
        s0 += g;
        s1 += ts[base + r] * g;
    }
    p0[chunk * FD + col] = s0;
    p1[chunk * FD + col] = s1;
}

// k4b: exclusive scan of the 256 chunk-partials per column; totals -> Pex row 8192
__global__ __launch_bounds__(512) void k4b_scan(float* __restrict__ p0,
                                                float* __restrict__ p1,
                                                float* __restrict__ Pex0,
                                                float* __restrict__ Pex1){
    int tid = threadIdx.x;
    float* p  = (tid < 256) ? p0 : p1;
    float* Pt = (tid < 256) ? Pex0 : Pex1;
    int col = tid & 255;
    float run = 0.f;
    #pragma unroll 8
    for (int c = 0; c < 256; ++c){
        float v = p[c * FD + col];
        p[c * FD + col] = run;
        run += v;
    }
    Pt[(size_t)NR * FD + col] = run;
}

// k4c: fill exclusive column prefix sums Pex0/Pex1 rows 0..8191
__global__ __launch_bounds__(256) void k4c_fill(const float* __restrict__ Gs,
                                                const float* __restrict__ ts,
                                                const float* __restrict__ p0,
                                                const float* __restrict__ p1,
                                                float* __restrict__ Pex0,
                                                float* __restrict__ Pex1){
    int col = threadIdx.x;
    int chunk = blockIdx.x;
    int base = chunk * 32;
    float run0 = p0[chunk * FD + col];
    float run1 = p1[chunk * FD + col];
    #pragma unroll
    for (int r = 0; r < 32; ++r){
        size_t row = base + r;
        Pex0[row * FD + col] = run0;
        Pex1[row * FD + col] = run1;
        float g = Gs[row * FD + col];
        run0 += g;
        run1 += ts[row] * g;
    }
}

// ---------------------------------------------------------------------------
// k5: M[i][k] = (0.1*full + 0.9*active - diag_i*G[i][k]) / (N-1)
//   full   = (s_i+c)*T0[k] + T1[k]
//   active = (s_i+c)*(T0[k]-Pex0[pos_i][k]) + (T1[k]-Pex1[pos_i][k])
//   pos_i  = lower_bound(ts, -(s_i+c));  G[i] = Gs[rank[i]]
__global__ __launch_bounds__(256) void k5_build_m(
    const float* __restrict__ s, const float* __restrict__ t,
    const float* __restrict__ ts, const int* __restrict__ rank,
    const float* __restrict__ Gs,
    const float* __restrict__ Pex0, const float* __restrict__ Pex1,
    const float* __restrict__ b3, float* __restrict__ M)
{
    __shared__ float lts[NR];
    for (int i = threadIdx.x; i < NR; i += 256) lts[i] = ts[i];
    __syncthreads();
    int col = threadIdx.x;
    float c = b3[0];
    float T0 = Pex0[(size_t)NR * FD + col];
    float T1 = Pex1[(size_t)NR * FD + col];
    const float inv = 1.0f / (float)(NR - 1);
    int rowBase = blockIdx.x * 32;
    for (int r = 0; r < 32; ++r){
        int i = rowBase + r;
        float si = s[i], ti = t[i];
        float sic = si + c;
        float theta = -sic;
        int lo = 0, hi = NR;
        while (lo < hi){
            int mid = (lo + hi) >> 1;
            if (lts[mid] < theta) lo = mid + 1; else hi = mid;
        }
        int pos = lo;
        float P0 = Pex0[(size_t)pos * FD + col];
        float P1 = Pex1[(size_t)pos * FD + col];
        float g  = Gs[(size_t)rank[i] * FD + col];
        float diag = leaky_f(sic + ti);
        float full = sic * T0 + T1;
        float act  = sic * (T0 - P0) + (T1 - P1);
        M[(size_t)i * FD + col] = (0.1f * full + 0.9f * act - diag * g) * inv;
    }
}

// ---------------------------------------------------------------------------
extern "C" void kernel_launch(void* const* d_in, const int* in_sizes, int n_in,
                              void* d_out, int out_size, void* d_ws, size_t ws_size,
                              hipStream_t stream)
{
    const float* x  = (const float*)d_in[0];
    const float* W3 = (const float*)d_in[1];
    const float* b3 = (const float*)d_in[2];
    const float* W6 = (const float*)d_in[3];
    const float* b6 = (const float*)d_in[4];
    const float* W5 = (const float*)d_in[5];
    const float* b5 = (const float*)d_in[6];
    float* out = (float*)d_out;

    char* ws = (char*)d_ws;
    size_t off = 0;
    auto alloc = [&](size_t bytes) -> void* {
        void* p = ws + off;
        off += (bytes + 255) & ~(size_t)255;
        return p;
    };
    float* s    = (float*)alloc(NR * 4);
    float* t    = (float*)alloc(NR * 4);
    float* ts   = (float*)alloc(NR * 4);
    int*   rank = (int*)  alloc(NR * 4);
    float* p0   = (float*)alloc(256 * FD * 4);
    float* p1   = (float*)alloc(256 * FD * 4);
    short* W6hi = (short*)alloc(FD * FD * 2);
    short* W6lo = (short*)alloc(FD * FD * 2);
    short* W5hi = (short*)alloc(FD * FD * 2);
    short* W5lo = (short*)alloc(FD * FD * 2);
    float* Gs   = (float*)alloc((size_t)NR * FD * 4);
    float* Pex0 = (float*)alloc((size_t)(NR + 1) * FD * 4);
    float* Pex1 = (float*)alloc((size_t)(NR + 1) * FD * 4);
    float* M    = (float*)alloc((size_t)NR * FD * 4);
    (void)ws_size; (void)in_sizes; (void)n_in; (void)out_size;

    k0_prep<<<dim3(FD * FD / 256), dim3(256), 0, stream>>>(W6, W6hi, W6lo, FD * FD);
    k0_prep<<<dim3(FD * FD / 256), dim3(256), 0, stream>>>(W5, W5hi, W5lo, FD * FD);
    k1_st<<<dim3(NR / 4), dim3(256), 0, stream>>>(x, W3, s, t);
    k3_rank<<<dim3(NR / 256), dim3(256), 0, stream>>>(t, ts, rank);
    // G = leaky(x@W6^T + b6), rows scattered into sorted-by-t order: Gs[rank[i]] = G[i]
    gemm_nt<true, false><<<dim3(128, 2), dim3(256), 0, stream>>>(
        x, W6hi, W6lo, b6, nullptr, rank, Gs);
    k4a_partial<<<dim3(256), dim3(256), 0, stream>>>(Gs, ts, p0, p1);
    k4b_scan<<<dim3(1), dim3(512), 0, stream>>>(p0, p1, Pex0, Pex1);
    k4c_fill<<<dim3(256), dim3(256), 0, stream>>>(Gs, ts, p0, p1, Pex0, Pex1);
    k5_build_m<<<dim3(NR / 32), dim3(256), 0, stream>>>(
        s, t, ts, rank, Gs, Pex0, Pex1, b3, M);
    // out = leaky(M@W5^T + b5) + x
    gemm_nt<false, true><<<dim3(128, 2), dim3(256), 0, stream>>>(
        M, W5hi, W5lo, b5, x, nullptr, out);
}

// Round 2
// 191.260 us; speedup vs baseline: 2.0649x; 2.0649x over previous
//
#include <hip/hip_runtime.h>
#include <stdint.h>

#define NR 8192
#define FD 256

typedef __attribute__((ext_vector_type(8))) short bf16x8;
typedef __attribute__((ext_vector_type(4))) float f32x4;

__device__ __forceinline__ float leaky_f(float z){ return z >= 0.0f ? z : 0.1f * z; }

__device__ __forceinline__ unsigned short f2bf(float f){
    union { float f; uint32_t u; } v; v.f = f;
    uint32_t r = v.u + 0x7fffu + ((v.u >> 16) & 1u);
    return (unsigned short)(r >> 16);
}
__device__ __forceinline__ float bf2f(unsigned short h){
    union { uint32_t u; float f; } v; v.u = ((uint32_t)h) << 16;
    return v.f;
}

// ---------------------------------------------------------------------------
// k0: precompute bf16 hi/lo split of a weight matrix
__global__ void k0_prep(const float* __restrict__ W, short* __restrict__ hi,
                        short* __restrict__ lo, int n){
    int i = blockIdx.x * 256 + threadIdx.x;
    if (i < n){
        float v = W[i];
        unsigned short h = f2bf(v);
        hi[i] = (short)h;
        lo[i] = (short)f2bf(v - bf2f(h));
    }
}

// ---------------------------------------------------------------------------
// k1: s = x@Wa, t = x@Wb. One wave per row. Also zero-inits rank[] for k3a.
__global__ __launch_bounds__(256) void k1_st(const float* __restrict__ x,
                                             const float* __restrict__ W3,
                                             float* __restrict__ s,
                                             float* __restrict__ t,
                                             int* __restrict__ rank){
    int wave = threadIdx.x >> 6;
    int lane = threadIdx.x & 63;
    int row  = blockIdx.x * 4 + wave;
    const float* xr = x + (size_t)row * FD;
    float as = 0.0f, at = 0.0f;
    #pragma unroll
    for (int m = 0; m < 4; ++m){
        int kk = lane + 64 * m;
        float xv = xr[kk];
        as += xv * W3[kk];
        at += xv * W3[FD + kk];
    }
    #pragma unroll
    for (int off = 32; off > 0; off >>= 1){
        as += __shfl_xor(as, off, 64);
        at += __shfl_xor(at, off, 64);
    }
    if (lane == 0){ s[row] = as; t[row] = at; rank[row] = 0; }
}

// ---------------------------------------------------------------------------
// k3a: 2D-parallel counting-rank of t (ascending, index tie-break).
// Block (bx,by): j-group bx (256 j's) vs segment by (256 values, LDS-staged).
// Partial counts accumulated with exact int atomics -> identical ranks to a
// serial count, but 1024 blocks instead of 32 (occupancy fix).
__global__ __launch_bounds__(256) void k3a_count(const float* __restrict__ t,
                                                 int* __restrict__ rank){
    __shared__ __align__(16) float seg[256];
    int tid = threadIdx.x;
    int j = blockIdx.x * 256 + tid;
    int segBase = blockIdx.y * 256;
    seg[tid] = t[segBase + tid];
    __syncthreads();
    float tj = t[j];
    int cnt = 0;
    #pragma unroll 16
    for (int r = 0; r < 256; r += 4){
        float4 v = *reinterpret_cast<const float4*>(&seg[r]);
        int jp = segBase + r;
        cnt += (v.x < tj) || (v.x == tj && (jp + 0) < j);
        cnt += (v.y < tj) || (v.y == tj && (jp + 1) < j);
        cnt += (v.z < tj) || (v.z == tj && (jp + 2) < j);
        cnt += (v.w < tj) || (v.w == tj && (jp + 3) < j);
    }
    atomicAdd(&rank[j], cnt);
}

// k3b: scatter sorted values: ts[rank[j]] = t[j]
__global__ __launch_bounds__(256) void k3b_scatter(const float* __restrict__ t,
                                                   const int* __restrict__ rank,
                                                   float* __restrict__ ts){
    int j = blockIdx.x * 256 + threadIdx.x;
    ts[rank[j]] = t[j];
}

// ---------------------------------------------------------------------------
// gemm_nt: out[i][n] = leaky( sum_k A[i][k]*Wt[n][k] + bias[n] ) (+ addend)
// Split-bf16 MFMA (hi*hi + lo*hi + hi*lo) for ~f32 accuracy.
template<bool SCATTER, bool ADD>
__global__ __launch_bounds__(256) void gemm_nt(
    const float* __restrict__ A,
    const short* __restrict__ Whi, const short* __restrict__ Wlo,
    const float* __restrict__ bias,
    const float* __restrict__ addend,
    const int* __restrict__ perm,
    float* __restrict__ out)
{
    int wave = threadIdx.x >> 6;
    int lane = threadIdx.x & 63;
    int rowBase = blockIdx.x * 64 + wave * 16;
    int colBase = blockIdx.y * 128;
    int m16 = lane & 15;
    int k8  = (lane >> 4) * 8;

    f32x4 acc[8];
    #pragma unroll
    for (int c = 0; c < 8; ++c) acc[c] = (f32x4){0.f, 0.f, 0.f, 0.f};

    const float* arow = A + (size_t)(rowBase + m16) * FD + k8;

    #pragma unroll
    for (int ks = 0; ks < 8; ++ks){
        int kb = ks * 32;
        float4 a0 = *reinterpret_cast<const float4*>(arow + kb);
        float4 a1 = *reinterpret_cast<const float4*>(arow + kb + 4);
        float a8[8] = {a0.x, a0.y, a0.z, a0.w, a1.x, a1.y, a1.z, a1.w};
        bf16x8 ahi, alo;
        #pragma unroll
        for (int e = 0; e < 8; ++e){
            unsigned short h = f2bf(a8[e]);
            ahi[e] = (short)h;
            alo[e] = (short)f2bf(a8[e] - bf2f(h));
        }
        #pragma unroll
        for (int c = 0; c < 8; ++c){
            size_t boff = (size_t)(colBase + c * 16 + m16) * FD + k8 + kb;
            bf16x8 bhi = *reinterpret_cast<const bf16x8*>(Whi + boff);
            bf16x8 blo = *reinterpret_cast<const bf16x8*>(Wlo + boff);
            acc[c] = __builtin_amdgcn_mfma_f32_16x16x32_bf16(ahi, bhi, acc[c], 0, 0, 0);
            acc[c] = __builtin_amdgcn_mfma_f32_16x16x32_bf16(alo, bhi, acc[c], 0, 0, 0);
            acc[c] = __builtin_amdgcn_mfma_f32_16x16x32_bf16(ahi, blo, acc[c], 0, 0, 0);
        }
    }

    int rq = (lane >> 4) * 4;
    #pragma unroll
    for (int c = 0; c < 8; ++c){
        int gcol = colBase + c * 16 + m16;
        float bs = bias[gcol];
        #pragma unroll
        for (int j = 0; j < 4; ++j){
            int grow = rowBase + rq + j;
            float v = leaky_f(acc[c][j] + bs);
            if (ADD) v += addend[(size_t)grow * FD + gcol];
            int orow = SCATTER ? perm[grow] : grow;
            out[(size_t)orow * FD + gcol] = v;
        }
    }
}

// ---------------------------------------------------------------------------
// k4a: per-chunk (32 rows) column sums of Gs and ts*Gs
__global__ __launch_bounds__(256) void k4a_partial(const float* __restrict__ Gs,
                                                   const float* __restrict__ ts,
                                                   float* __restrict__ p0,
                                                   float* __restrict__ p1){
    int col = threadIdx.x;
    int chunk = blockIdx.x;
    int base = chunk * 32;
    float s0 = 0.f, s1 = 0.f;
    #pragma unroll
    for (int r = 0; r < 32; ++r){
        float g = Gs[(size_t)(base + r) * FD + col];
        s0 += g;
        s1 += ts[base + r] * g;
    }
    p0[chunk * FD + col] = s0;
    p1[chunk * FD + col] = s1;
}

// k4b: wave-parallel exclusive scan of 256 chunk-partials per column.
// grid(512) x 64 threads: bid<256 -> p0 column bid, else p1 column bid-256.
// 4 elements/lane local scan + __shfl_up wave scan; totals -> Pex row 8192.
__global__ __launch_bounds__(64) void k4b_scan(float* __restrict__ p0,
                                               float* __restrict__ p1,
                                               float* __restrict__ Pex0,
                                               float* __restrict__ Pex1){
    int bid  = blockIdx.x;
    int lane = threadIdx.x;
    float* p  = (bid < 256) ? p0 : p1;
    float* Pt = (bid < 256) ? Pex0 : Pex1;
    int col = bid & 255;
    int c0 = lane * 4;
    float v0 = p[(size_t)(c0 + 0) * FD + col];
    float v1 = p[(size_t)(c0 + 1) * FD + col];
    float v2 = p[(size_t)(c0 + 2) * FD + col];
    float v3 = p[(size_t)(c0 + 3) * FD + col];
    float s1 = v0 + v1, s2 = s1 + v2, s3 = s2 + v3;
    float x = s3;
    #pragma unroll
    for (int off = 1; off < 64; off <<= 1){
        float n = __shfl_up(x, off, 64);
        if (lane >= off) x += n;
    }
    float excl = x - s3;
    p[(size_t)(c0 + 0) * FD + col] = excl;
    p[(size_t)(c0 + 1) * FD + col] = excl + v0;
    p[(size_t)(c0 + 2) * FD + col] = excl + s1;
    p[(size_t)(c0 + 3) * FD + col] = excl + s2;
    if (lane == 63) Pt[(size_t)NR * FD + col] = x;
}

// k4c: fill exclusive column prefix sums Pex0/Pex1 rows 0..8191
__global__ __launch_bounds__(256) void k4c_fill(const float* __restrict__ Gs,
                                                const float* __restrict__ ts,
                                                const float* __restrict__ p0,
                                                const float* __restrict__ p1,
                                                float* __restrict__ Pex0,
                                                float* __restrict__ Pex1){
    int col = threadIdx.x;
    int chunk = blockIdx.x;
    int base = chunk * 32;
    float run0 = p0[chunk * FD + col];
    float run1 = p1[chunk * FD + col];
    #pragma unroll
    for (int r = 0; r < 32; ++r){
        size_t row = base + r;
        Pex0[row * FD + col] = run0;
        Pex1[row * FD + col] = run1;
        float g = Gs[row * FD + col];
        run0 += g;
        run1 += ts[row] * g;
    }
}

// ---------------------------------------------------------------------------
// k5: M[i][k] = (0.1*full + 0.9*active - diag_i*G[i][k]) / (N-1)
__global__ __launch_bounds__(256) void k5_build_m(
    const float* __restrict__ s, const float* __restrict__ t,
    const float* __restrict__ ts, const int* __restrict__ rank,
    const float* __restrict__ Gs,
    const float* __restrict__ Pex0, const float* __restrict__ Pex1,
    const float* __restrict__ b3, float* __restrict__ M)
{
    __shared__ float lts[NR];
    for (int i = threadIdx.x; i < NR; i += 256) lts[i] = ts[i];
    __syncthreads();
    int col = threadIdx.x;
    float c = b3[0];
    float T0 = Pex0[(size_t)NR * FD + col];
    float T1 = Pex1[(size_t)NR * FD + col];
    const float inv = 1.0f / (float)(NR - 1);
    int rowBase = blockIdx.x * 32;
    for (int r = 0; r < 32; ++r){
        int i = rowBase + r;
        float si = s[i], ti = t[i];
        float sic = si + c;
        float theta = -sic;
        int lo = 0, hi = NR;
        while (lo < hi){
            int mid = (lo + hi) >> 1;
            if (lts[mid] < theta) lo = mid + 1; else hi = mid;
        }
        int pos = lo;
        float P0 = Pex0[(size_t)pos * FD + col];
        float P1 = Pex1[(size_t)pos * FD + col];
        float g  = Gs[(size_t)rank[i] * FD + col];
        float diag = leaky_f(sic + ti);
        float full = sic * T0 + T1;
        float act  = sic * (T0 - P0) + (T1 - P1);
        M[(size_t)i * FD + col] = (0.1f * full + 0.9f * act - diag * g) * inv;
    }
}

// ---------------------------------------------------------------------------
extern "C" void kernel_launch(void* const* d_in, const int* in_sizes, int n_in,
                              void* d_out, int out_size, void* d_ws, size_t ws_size,
                              hipStream_t stream)
{
    const float* x  = (const float*)d_in[0];
    const float* W3 = (const float*)d_in[1];
    const float* b3 = (const float*)d_in[2];
    const float* W6 = (const float*)d_in[3];
    const float* b6 = (const float*)d_in[4];
    const float* W5 = (const float*)d_in[5];
    const float* b5 = (const float*)d_in[6];
    float* out = (float*)d_out;

    char* ws = (char*)d_ws;
    size_t off = 0;
    auto alloc = [&](size_t bytes) -> void* {
        void* p = ws + off;
        off += (bytes + 255) & ~(size_t)255;
        return p;
    };
    float* s    = (float*)alloc(NR * 4);
    float* t    = (float*)alloc(NR * 4);
    float* ts   = (float*)alloc(NR * 4);
    int*   rank = (int*)  alloc(NR * 4);
    float* p0   = (float*)alloc(256 * FD * 4);
    float* p1   = (float*)alloc(256 * FD * 4);
    short* W6hi = (short*)alloc(FD * FD * 2);
    short* W6lo = (short*)alloc(FD * FD * 2);
    short* W5hi = (short*)alloc(FD * FD * 2);
    short* W5lo = (short*)alloc(FD * FD * 2);
    float* Gs   = (float*)alloc((size_t)NR * FD * 4);
    float* Pex0 = (float*)alloc((size_t)(NR + 1) * FD * 4);
    float* Pex1 = (float*)alloc((size_t)(NR + 1) * FD * 4);
    float* M    = (float*)alloc((size_t)NR * FD * 4);
    (void)ws_size; (void)in_sizes; (void)n_in; (void)out_size;

    k0_prep<<<dim3(FD * FD / 256), dim3(256), 0, stream>>>(W6, W6hi, W6lo, FD * FD);
    k0_prep<<<dim3(FD * FD / 256), dim3(256), 0, stream>>>(W5, W5hi, W5lo, FD * FD);
    k1_st<<<dim3(NR / 4), dim3(256), 0, stream>>>(x, W3, s, t, rank);
    k3a_count<<<dim3(32, 32), dim3(256), 0, stream>>>(t, rank);
    k3b_scatter<<<dim3(NR / 256), dim3(256), 0, stream>>>(t, rank, ts);
    // G = leaky(x@W6^T + b6), rows scattered into sorted-by-t order
    gemm_nt<true, false><<<dim3(128, 2), dim3(256), 0, stream>>>(
        x, W6hi, W6lo, b6, nullptr, rank, Gs);
    k4a_partial<<<dim3(256), dim3(256), 0, stream>>>(Gs, ts, p0, p1);
    k4b_scan<<<dim3(512), dim3(64), 0, stream>>>(p0, p1, Pex0, Pex1);
    k4c_fill<<<dim3(256), dim3(256), 0, stream>>>(Gs, ts, p0, p1, Pex0, Pex1);
    k5_build_m<<<dim3(NR / 32), dim3(256), 0, stream>>>(
        s, t, ts, rank, Gs, Pex0, Pex1, b3, M);
    // out = leaky(M@W5^T + b5) + x
    gemm_nt<false, true><<<dim3(128, 2), dim3(256), 0, stream>>>(
        M, W5hi, W5lo, b5, x, nullptr, out);
}

// Round 3
// 172.191 us; speedup vs baseline: 2.2936x; 1.1107x over previous
//
#include <hip/hip_runtime.h>
#include <stdint.h>

#define NR 8192
#define FD 256
#define NCH 1024   // 8-row chunks

typedef __attribute__((ext_vector_type(8))) short bf16x8;
typedef __attribute__((ext_vector_type(4))) float f32x4;

__device__ __forceinline__ float leaky_f(float z){ return z >= 0.0f ? z : 0.1f * z; }

__device__ __forceinline__ unsigned short f2bf(float f){
    union { float f; uint32_t u; } v; v.f = f;
    uint32_t r = v.u + 0x7fffu + ((v.u >> 16) & 1u);
    return (unsigned short)(r >> 16);
}
__device__ __forceinline__ float bf2f(unsigned short h){
    union { uint32_t u; float f; } v; v.u = ((uint32_t)h) << 16;
    return v.f;
}

// ---------------------------------------------------------------------------
// k0: bf16 hi/lo split of a weight matrix
__global__ void k0_prep(const float* __restrict__ W, short* __restrict__ hi,
                        short* __restrict__ lo, int n){
    int i = blockIdx.x * 256 + threadIdx.x;
    if (i < n){
        float v = W[i];
        unsigned short h = f2bf(v);
        hi[i] = (short)h;
        lo[i] = (short)f2bf(v - bf2f(h));
    }
}

// ---------------------------------------------------------------------------
// k1: s = x@Wa, t = x@Wb (float4-vectorized); zero-inits rank[] for k3a.
__global__ __launch_bounds__(256) void k1_st(const float* __restrict__ x,
                                             const float* __restrict__ W3,
                                             float* __restrict__ s,
                                             float* __restrict__ t,
                                             int* __restrict__ rank){
    int wave = threadIdx.x >> 6;
    int lane = threadIdx.x & 63;
    int row  = blockIdx.x * 4 + wave;
    const float4* xr = (const float4*)(x + (size_t)row * FD);
    const float4* wa = (const float4*)W3;
    const float4* wb = (const float4*)(W3 + FD);
    float4 xv = xr[lane], av = wa[lane], bv = wb[lane];
    float as = xv.x*av.x + xv.y*av.y + xv.z*av.z + xv.w*av.w;
    float at = xv.x*bv.x + xv.y*bv.y + xv.z*bv.z + xv.w*bv.w;
    #pragma unroll
    for (int off = 32; off > 0; off >>= 1){
        as += __shfl_xor(as, off, 64);
        at += __shfl_xor(at, off, 64);
    }
    if (lane == 0){ s[row] = as; t[row] = at; rank[row] = 0; }
}

// ---------------------------------------------------------------------------
// k3a: 2D-parallel counting-rank of t (ascending, index tie-break), exact int
// atomics. Grid (32,32) = 1024 blocks.
__global__ __launch_bounds__(256) void k3a_count(const float* __restrict__ t,
                                                 int* __restrict__ rank){
    __shared__ __align__(16) float seg[256];
    int tid = threadIdx.x;
    int j = blockIdx.x * 256 + tid;
    int segBase = blockIdx.y * 256;
    seg[tid] = t[segBase + tid];
    __syncthreads();
    float tj = t[j];
    int cnt = 0;
    #pragma unroll 16
    for (int r = 0; r < 256; r += 4){
        float4 v = *reinterpret_cast<const float4*>(&seg[r]);
        int jp = segBase + r;
        cnt += (v.x < tj) || (v.x == tj && (jp + 0) < j);
        cnt += (v.y < tj) || (v.y == tj && (jp + 1) < j);
        cnt += (v.z < tj) || (v.z == tj && (jp + 2) < j);
        cnt += (v.w < tj) || (v.w == tj && (jp + 3) < j);
    }
    atomicAdd(&rank[j], cnt);
}

// k3b: ts[rank[j]] = t[j]
__global__ __launch_bounds__(256) void k3b_scatter(const float* __restrict__ t,
                                                   const int* __restrict__ rank,
                                                   float* __restrict__ ts){
    int j = blockIdx.x * 256 + threadIdx.x;
    ts[rank[j]] = t[j];
}

// ---------------------------------------------------------------------------
// gemm_nt: out[i][n] = leaky( sum_k A[i][k]*Wt[n][k] + bias[n] ) (+ addend)
// Split-bf16 MFMA. 64x64 tile/block, 4 waves (each 16 rows x 64 cols).
// Grid (FD/64=4 colblocks fastest, NR/64=128 rowblocks) = 512 blocks.
template<bool SCATTER, bool ADD>
__global__ __launch_bounds__(256) void gemm_nt(
    const float* __restrict__ A,
    const short* __restrict__ Whi, const short* __restrict__ Wlo,
    const float* __restrict__ bias,
    const float* __restrict__ addend,
    const int* __restrict__ perm,
    float* __restrict__ out)
{
    int wave = threadIdx.x >> 6;
    int lane = threadIdx.x & 63;
    int rowBase = blockIdx.y * 64 + wave * 16;
    int colBase = blockIdx.x * 64;
    int m16 = lane & 15;
    int k8  = (lane >> 4) * 8;

    f32x4 acc[4];
    #pragma unroll
    for (int c = 0; c < 4; ++c) acc[c] = (f32x4){0.f, 0.f, 0.f, 0.f};

    const float* arow = A + (size_t)(rowBase + m16) * FD + k8;

    #pragma unroll
    for (int ks = 0; ks < 8; ++ks){
        int kb = ks * 32;
        float4 a0 = *reinterpret_cast<const float4*>(arow + kb);
        float4 a1 = *reinterpret_cast<const float4*>(arow + kb + 4);
        float a8[8] = {a0.x, a0.y, a0.z, a0.w, a1.x, a1.y, a1.z, a1.w};
        bf16x8 ahi, alo;
        #pragma unroll
        for (int e = 0; e < 8; ++e){
            unsigned short h = f2bf(a8[e]);
            ahi[e] = (short)h;
            alo[e] = (short)f2bf(a8[e] - bf2f(h));
        }
        #pragma unroll
        for (int c = 0; c < 4; ++c){
            size_t boff = (size_t)(colBase + c * 16 + m16) * FD + k8 + kb;
            bf16x8 bhi = *reinterpret_cast<const bf16x8*>(Whi + boff);
            bf16x8 blo = *reinterpret_cast<const bf16x8*>(Wlo + boff);
            acc[c] = __builtin_amdgcn_mfma_f32_16x16x32_bf16(ahi, bhi, acc[c], 0, 0, 0);
            acc[c] = __builtin_amdgcn_mfma_f32_16x16x32_bf16(alo, bhi, acc[c], 0, 0, 0);
            acc[c] = __builtin_amdgcn_mfma_f32_16x16x32_bf16(ahi, blo, acc[c], 0, 0, 0);
        }
    }

    int rq = (lane >> 4) * 4;
    #pragma unroll
    for (int c = 0; c < 4; ++c){
        int gcol = colBase + c * 16 + m16;
        float bs = bias[gcol];
        #pragma unroll
        for (int j = 0; j < 4; ++j){
            int grow = rowBase + rq + j;
            float v = leaky_f(acc[c][j] + bs);
            if (ADD) v += addend[(size_t)grow * FD + gcol];
            int orow = SCATTER ? perm[grow] : grow;
            out[(size_t)orow * FD + gcol] = v;
        }
    }
}

// ---------------------------------------------------------------------------
// k4a: per-chunk (8 rows) column sums of Gs and ts*Gs. Grid 1024.
__global__ __launch_bounds__(256) void k4a_partial(const float* __restrict__ Gs,
                                                   const float* __restrict__ ts,
                                                   float* __restrict__ p0,
                                                   float* __restrict__ p1){
    int col = threadIdx.x;
    int chunk = blockIdx.x;
    int base = chunk * 8;
    float s0 = 0.f, s1 = 0.f;
    #pragma unroll
    for (int r = 0; r < 8; ++r){
        float g = Gs[(size_t)(base + r) * FD + col];
        s0 += g;
        s1 += ts[base + r] * g;
    }
    p0[(size_t)chunk * FD + col] = s0;
    p1[(size_t)chunk * FD + col] = s1;
}

// k4b: exclusive scan of 1024 chunk-partials per column, in place; grand
// total -> row 1024. Grid 512 single-wave blocks (bid<256 -> p0, else p1).
__global__ __launch_bounds__(64) void k4b_scan(float* __restrict__ p0,
                                               float* __restrict__ p1){
    int bid  = blockIdx.x;
    int lane = threadIdx.x;
    float* p = (bid < 256) ? p0 : p1;
    int col = bid & 255;
    int c0 = lane * 16;
    float v[16];
    #pragma unroll
    for (int k = 0; k < 16; ++k) v[k] = p[(size_t)(c0 + k) * FD + col];
    float run = 0.f;
    #pragma unroll
    for (int k = 0; k < 16; ++k) run += v[k];
    float x = run;
    #pragma unroll
    for (int off = 1; off < 64; off <<= 1){
        float n = __shfl_up(x, off, 64);
        if (lane >= off) x += n;
    }
    float e = x - run;   // exclusive base for this lane's 16 chunks
    #pragma unroll
    for (int k = 0; k < 16; ++k){
        p[(size_t)(c0 + k) * FD + col] = e;
        e += v[k];
    }
    if (lane == 63) p[(size_t)NCH * FD + col] = x;  // grand total
}

// ---------------------------------------------------------------------------
// k5a: per-row scalars: pos = lower_bound(ts, -(s_i+c)), sic, diag, rank.
__global__ __launch_bounds__(256) void k5a_pos(const float* __restrict__ s,
                                               const float* __restrict__ t,
                                               const float* __restrict__ b3,
                                               const float* __restrict__ ts,
                                               const int* __restrict__ rank,
                                               float4* __restrict__ scal){
    int i = blockIdx.x * 256 + threadIdx.x;
    float c = b3[0];
    float sic = s[i] + c;
    float theta = -sic;
    int lo = 0, hi = NR;
    while (lo < hi){
        int mid = (lo + hi) >> 1;
        if (ts[mid] < theta) lo = mid + 1; else hi = mid;
    }
    float diag = leaky_f(sic + t[i]);
    scal[i] = make_float4(sic, diag, __int_as_float(lo), __int_as_float(rank[i]));
}

// k5b: M[i][k] = (0.1*full + 0.9*active - diag_i*G[i][k]) / (N-1), streaming.
// P at pos = scanned 8-chunk base + in-chunk tail (uniform across block).
// Grid 1024 blocks x 8 rows.
__global__ __launch_bounds__(256) void k5b_build(
    const float4* __restrict__ scal, const float* __restrict__ ts,
    const float* __restrict__ Gs,
    const float* __restrict__ p0, const float* __restrict__ p1,
    float* __restrict__ M)
{
    int col = threadIdx.x;
    int i0 = blockIdx.x * 8;
    float T0 = p0[(size_t)NCH * FD + col];
    float T1 = p1[(size_t)NCH * FD + col];
    const float inv = 1.0f / (float)(NR - 1);
    #pragma unroll
    for (int r = 0; r < 8; ++r){
        int i = i0 + r;
        float4 sc = scal[i];
        float sic = sc.x, diag = sc.y;
        int pos = __float_as_int(sc.z);
        int rk  = __float_as_int(sc.w);
        int ch  = pos >> 3;
        float P0 = p0[(size_t)ch * FD + col];
        float P1 = p1[(size_t)ch * FD + col];
        for (int r2 = ch * 8; r2 < pos; ++r2){   // <=7 iters, uniform
            float g2 = Gs[(size_t)r2 * FD + col];
            P0 += g2;
            P1 += ts[r2] * g2;
        }
        float g = Gs[(size_t)rk * FD + col];
        float full = sic * T0 + T1;
        float act  = sic * (T0 - P0) + (T1 - P1);
        M[(size_t)i * FD + col] = (0.1f * full + 0.9f * act - diag * g) * inv;
    }
}

// ---------------------------------------------------------------------------
extern "C" void kernel_launch(void* const* d_in, const int* in_sizes, int n_in,
                              void* d_out, int out_size, void* d_ws, size_t ws_size,
                              hipStream_t stream)
{
    const float* x  = (const float*)d_in[0];
    const float* W3 = (const float*)d_in[1];
    const float* b3 = (const float*)d_in[2];
    const float* W6 = (const float*)d_in[3];
    const float* b6 = (const float*)d_in[4];
    const float* W5 = (const float*)d_in[5];
    const float* b5 = (const float*)d_in[6];
    float* out = (float*)d_out;

    char* ws = (char*)d_ws;
    size_t off = 0;
    auto alloc = [&](size_t bytes) -> void* {
        void* p = ws + off;
        off += (bytes + 255) & ~(size_t)255;
        return p;
    };
    float*  s    = (float*)alloc(NR * 4);
    float*  t    = (float*)alloc(NR * 4);
    float*  ts   = (float*)alloc(NR * 4);
    int*    rank = (int*)  alloc(NR * 4);
    float*  p0   = (float*)alloc((size_t)(NCH + 1) * FD * 4);
    float*  p1   = (float*)alloc((size_t)(NCH + 1) * FD * 4);
    short*  W6hi = (short*)alloc(FD * FD * 2);
    short*  W6lo = (short*)alloc(FD * FD * 2);
    short*  W5hi = (short*)alloc(FD * FD * 2);
    short*  W5lo = (short*)alloc(FD * FD * 2);
    float4* scal = (float4*)alloc(NR * 16);
    float*  Gs   = (float*)alloc((size_t)NR * FD * 4);
    float*  M    = (float*)alloc((size_t)NR * FD * 4);
    (void)ws_size; (void)in_sizes; (void)n_in; (void)out_size;

    k0_prep<<<dim3(FD * FD / 256), dim3(256), 0, stream>>>(W6, W6hi, W6lo, FD * FD);
    k0_prep<<<dim3(FD * FD / 256), dim3(256), 0, stream>>>(W5, W5hi, W5lo, FD * FD);
    k1_st<<<dim3(NR / 4), dim3(256), 0, stream>>>(x, W3, s, t, rank);
    k3a_count<<<dim3(32, 32), dim3(256), 0, stream>>>(t, rank);
    k3b_scatter<<<dim3(NR / 256), dim3(256), 0, stream>>>(t, rank, ts);
    // G = leaky(x@W6^T + b6), rows scattered into sorted-by-t order
    gemm_nt<true, false><<<dim3(FD / 64, NR / 64), dim3(256), 0, stream>>>(
        x, W6hi, W6lo, b6, nullptr, rank, Gs);
    k4a_partial<<<dim3(NCH), dim3(256), 0, stream>>>(Gs, ts, p0, p1);
    k4b_scan<<<dim3(512), dim3(64), 0, stream>>>(p0, p1);
    k5a_pos<<<dim3(NR / 256), dim3(256), 0, stream>>>(s, t, b3, ts, rank, scal);
    k5b_build<<<dim3(NR / 8), dim3(256), 0, stream>>>(scal, ts, Gs, p0, p1, M);
    // out = leaky(M@W5^T + b5) + x
    gemm_nt<false, true><<<dim3(FD / 64, NR / 64), dim3(256), 0, stream>>>(
        M, W5hi, W5lo, b5, x, nullptr, out);
}

// Round 6
// 166.721 us; speedup vs baseline: 2.3689x; 1.0328x over previous
//
#include <hip/hip_runtime.h>
#include <stdint.h>

#define NR 8192
#define FD 256
#define NCH 1024   // 8-row chunks

typedef __attribute__((ext_vector_type(8))) short bf16x8;
typedef __attribute__((ext_vector_type(4))) float f32x4;

__device__ __forceinline__ float leaky_f(float z){ return z >= 0.0f ? z : 0.1f * z; }

__device__ __forceinline__ unsigned short f2bf(float f){
    union { float f; uint32_t u; } v; v.f = f;
    uint32_t r = v.u + 0x7fffu + ((v.u >> 16) & 1u);
    return (unsigned short)(r >> 16);
}
__device__ __forceinline__ float bf2f(unsigned short h){
    union { uint32_t u; float f; } v; v.u = ((uint32_t)h) << 16;
    return v.f;
}

// ---------------------------------------------------------------------------
// k0: bf16 hi/lo split of BOTH weight matrices (blockIdx.y selects matrix)
__global__ void k0_prep2(const float* __restrict__ W6, short* __restrict__ h6,
                         short* __restrict__ l6,
                         const float* __restrict__ W5, short* __restrict__ h5,
                         short* __restrict__ l5){
    int i = blockIdx.x * 256 + threadIdx.x;
    const float* W = blockIdx.y ? W5 : W6;
    short* hi = blockIdx.y ? h5 : h6;
    short* lo = blockIdx.y ? l5 : l6;
    float v = W[i];
    unsigned short h = f2bf(v);
    hi[i] = (short)h;
    lo[i] = (short)f2bf(v - bf2f(h));
}

// ---------------------------------------------------------------------------
// k1: s = x@Wa, t = x@Wb; ALSO emits bf16 hi/lo planes of x (pre-split for
// the MFMA GEMM) and zero-inits rank[]. One wave per row, float4 lanes.
__global__ __launch_bounds__(256) void k1_st(const float* __restrict__ x,
                                             const float* __restrict__ W3,
                                             float* __restrict__ s,
                                             float* __restrict__ t,
                                             int* __restrict__ rank,
                                             short* __restrict__ xhi,
                                             short* __restrict__ xlo){
    int wave = threadIdx.x >> 6;
    int lane = threadIdx.x & 63;
    int row  = blockIdx.x * 4 + wave;
    const float4* xr = (const float4*)(x + (size_t)row * FD);
    const float4* wa = (const float4*)W3;
    const float4* wb = (const float4*)(W3 + FD);
    float4 xv = xr[lane], av = wa[lane], bv = wb[lane];
    // split x -> bf16 hi/lo planes
    float xe[4] = {xv.x, xv.y, xv.z, xv.w};
    short4 h4, l4;
    short* hp = &h4.x; short* lp = &l4.x;
    #pragma unroll
    for (int e = 0; e < 4; ++e){
        unsigned short h = f2bf(xe[e]);
        hp[e] = (short)h;
        lp[e] = (short)f2bf(xe[e] - bf2f(h));
    }
    *reinterpret_cast<short4*>(xhi + (size_t)row * FD + lane * 4) = h4;
    *reinterpret_cast<short4*>(xlo + (size_t)row * FD + lane * 4) = l4;

    float as = xv.x*av.x + xv.y*av.y + xv.z*av.z + xv.w*av.w;
    float at = xv.x*bv.x + xv.y*bv.y + xv.z*bv.z + xv.w*bv.w;
    #pragma unroll
    for (int off = 32; off > 0; off >>= 1){
        as += __shfl_xor(as, off, 64);
        at += __shfl_xor(at, off, 64);
    }
    if (lane == 0){ s[row] = as; t[row] = at; rank[row] = 0; }
}

// ---------------------------------------------------------------------------
// k3a: 2D-parallel counting-rank of t (ascending, index tie-break), exact int
// atomics. Grid (32,32) = 1024 blocks.
__global__ __launch_bounds__(256) void k3a_count(const float* __restrict__ t,
                                                 int* __restrict__ rank){
    __shared__ __align__(16) float seg[256];
    int tid = threadIdx.x;
    int j = blockIdx.x * 256 + tid;
    int segBase = blockIdx.y * 256;
    seg[tid] = t[segBase + tid];
    __syncthreads();
    float tj = t[j];
    int cnt = 0;
    #pragma unroll 16
    for (int r = 0; r < 256; r += 4){
        float4 v = *reinterpret_cast<const float4*>(&seg[r]);
        int jp = segBase + r;
        cnt += (v.x < tj) || (v.x == tj && (jp + 0) < j);
        cnt += (v.y < tj) || (v.y == tj && (jp + 1) < j);
        cnt += (v.z < tj) || (v.z == tj && (jp + 2) < j);
        cnt += (v.w < tj) || (v.w == tj && (jp + 3) < j);
    }
    atomicAdd(&rank[j], cnt);
}

// k3b: ts[rank[j]] = t[j]
__global__ __launch_bounds__(256) void k3b_scatter(const float* __restrict__ t,
                                                   const int* __restrict__ rank,
                                                   float* __restrict__ ts){
    int j = blockIdx.x * 256 + threadIdx.x;
    ts[rank[j]] = t[j];
}

// ---------------------------------------------------------------------------
// gemm_nt: out[i][n] = leaky( sum_k A[i][k]*Wt[n][k] + bias[n] ) (+ addend)
// A pre-split into bf16 hi/lo planes -> NO conversion VALU in the loop.
// Split-bf16 MFMA (hi*hi + lo*hi + hi*lo). 64x64 tile/block, 4 waves.
// Grid (FD/64=4 colblocks fastest -> same-A blocks coschedule, NR/64=128).
template<bool SCATTER, bool ADD>
__global__ __launch_bounds__(256) void gemm_nt(
    const short* __restrict__ Ahi, const short* __restrict__ Alo,
    const short* __restrict__ Whi, const short* __restrict__ Wlo,
    const float* __restrict__ bias,
    const float* __restrict__ addend,
    const int* __restrict__ perm,
    float* __restrict__ out)
{
    int wave = threadIdx.x >> 6;
    int lane = threadIdx.x & 63;
    int rowBase = blockIdx.y * 64 + wave * 16;
    int colBase = blockIdx.x * 64;
    int m16 = lane & 15;
    int k8  = (lane >> 4) * 8;

    f32x4 acc[4];
    #pragma unroll
    for (int c = 0; c < 4; ++c) acc[c] = (f32x4){0.f, 0.f, 0.f, 0.f};

    const short* arh = Ahi + (size_t)(rowBase + m16) * FD + k8;
    const short* arl = Alo + (size_t)(rowBase + m16) * FD + k8;

    #pragma unroll
    for (int ks = 0; ks < 8; ++ks){
        int kb = ks * 32;
        bf16x8 ahi = *reinterpret_cast<const bf16x8*>(arh + kb);
        bf16x8 alo = *reinterpret_cast<const bf16x8*>(arl + kb);
        #pragma unroll
        for (int c = 0; c < 4; ++c){
            size_t boff = (size_t)(colBase + c * 16 + m16) * FD + k8 + kb;
            bf16x8 bhi = *reinterpret_cast<const bf16x8*>(Whi + boff);
            bf16x8 blo = *reinterpret_cast<const bf16x8*>(Wlo + boff);
            acc[c] = __builtin_amdgcn_mfma_f32_16x16x32_bf16(ahi, bhi, acc[c], 0, 0, 0);
            acc[c] = __builtin_amdgcn_mfma_f32_16x16x32_bf16(alo, bhi, acc[c], 0, 0, 0);
            acc[c] = __builtin_amdgcn_mfma_f32_16x16x32_bf16(ahi, blo, acc[c], 0, 0, 0);
        }
    }

    int rq = (lane >> 4) * 4;
    #pragma unroll
    for (int c = 0; c < 4; ++c){
        int gcol = colBase + c * 16 + m16;
        float bs = bias[gcol];
        #pragma unroll
        for (int j = 0; j < 4; ++j){
            int grow = rowBase + rq + j;
            float v = leaky_f(acc[c][j] + bs);
            if (ADD) v += addend[(size_t)grow * FD + gcol];
            int orow = SCATTER ? perm[grow] : grow;
            out[(size_t)orow * FD + gcol] = v;
        }
    }
}

// ---------------------------------------------------------------------------
// k4a: per-chunk (8 rows) column sums of Gs and ts*Gs. Grid 1024.
__global__ __launch_bounds__(256) void k4a_partial(const float* __restrict__ Gs,
                                                   const float* __restrict__ ts,
                                                   float* __restrict__ p0,
                                                   float* __restrict__ p1){
    int col = threadIdx.x;
    int chunk = blockIdx.x;
    int base = chunk * 8;
    float s0 = 0.f, s1 = 0.f;
    #pragma unroll
    for (int r = 0; r < 8; ++r){
        float g = Gs[(size_t)(base + r) * FD + col];
        s0 += g;
        s1 += ts[base + r] * g;
    }
    p0[(size_t)chunk * FD + col] = s0;
    p1[(size_t)chunk * FD + col] = s1;
}

// k4b: exclusive scan of 1024 chunk-partials per column, in place; grand
// total -> row 1024. Grid 512 single-wave blocks (bid<256 -> p0, else p1).
__global__ __launch_bounds__(64) void k4b_scan(float* __restrict__ p0,
                                               float* __restrict__ p1){
    int bid  = blockIdx.x;
    int lane = threadIdx.x;
    float* p = (bid < 256) ? p0 : p1;
    int col = bid & 255;
    int c0 = lane * 16;
    float v[16];
    #pragma unroll
    for (int k = 0; k < 16; ++k) v[k] = p[(size_t)(c0 + k) * FD + col];
    float run = 0.f;
    #pragma unroll
    for (int k = 0; k < 16; ++k) run += v[k];
    float x = run;
    #pragma unroll
    for (int off = 1; off < 64; off <<= 1){
        float n = __shfl_up(x, off, 64);
        if (lane >= off) x += n;
    }
    float e = x - run;
    #pragma unroll
    for (int k = 0; k < 16; ++k){
        p[(size_t)(c0 + k) * FD + col] = e;
        e += v[k];
    }
    if (lane == 63) p[(size_t)NCH * FD + col] = x;  // grand total
}

// ---------------------------------------------------------------------------
// k5a: per-row scalars: pos = lower_bound(ts, -(s_i+c)), sic, diag, rank.
// ts staged in LDS (32KB) to avoid dependent L2 reads in the search.
__global__ __launch_bounds__(256) void k5a_pos(const float* __restrict__ s,
                                               const float* __restrict__ t,
                                               const float* __restrict__ b3,
                                               const float* __restrict__ ts,
                                               const int* __restrict__ rank,
                                               float4* __restrict__ scal){
    __shared__ float lts[NR];
    for (int i = threadIdx.x; i < NR; i += 256) lts[i] = ts[i];
    __syncthreads();
    int i = blockIdx.x * 256 + threadIdx.x;
    float c = b3[0];
    float sic = s[i] + c;
    float theta = -sic;
    int lo = 0, hi = NR;
    while (lo < hi){
        int mid = (lo + hi) >> 1;
        if (lts[mid] < theta) lo = mid + 1; else hi = mid;
    }
    float diag = leaky_f(sic + t[i]);
    scal[i] = make_float4(sic, diag, __int_as_float(lo), __int_as_float(rank[i]));
}

// k5b: M[i][k] = (0.1*full + 0.9*active - diag_i*G[i][k]) / (N-1), streaming.
// Emits M directly as bf16 hi/lo planes (gemm2 consumes them, no f32 pass).
// Grid 1024 blocks x 8 rows.
__global__ __launch_bounds__(256) void k5b_build(
    const float4* __restrict__ scal, const float* __restrict__ ts,
    const float* __restrict__ Gs,
    const float* __restrict__ p0, const float* __restrict__ p1,
    short* __restrict__ Mhi, short* __restrict__ Mlo)
{
    int col = threadIdx.x;
    int i0 = blockIdx.x * 8;
    float T0 = p0[(size_t)NCH * FD + col];
    float T1 = p1[(size_t)NCH * FD + col];
    const float inv = 1.0f / (float)(NR - 1);
    #pragma unroll
    for (int r = 0; r < 8; ++r){
        int i = i0 + r;
        float4 sc = scal[i];
        float sic = sc.x, diag = sc.y;
        int pos = __float_as_int(sc.z);
        int rk  = __float_as_int(sc.w);
        int ch  = pos >> 3;
        float P0 = p0[(size_t)ch * FD + col];
        float P1 = p1[(size_t)ch * FD + col];
        for (int r2 = ch * 8; r2 < pos; ++r2){   // <=7 iters, uniform
            float g2 = Gs[(size_t)r2 * FD + col];
            P0 += g2;
            P1 += ts[r2] * g2;
        }
        float g = Gs[(size_t)rk * FD + col];
        float full = sic * T0 + T1;
        float act  = sic * (T0 - P0) + (T1 - P1);
        float m = (0.1f * full + 0.9f * act - diag * g) * inv;
        unsigned short h = f2bf(m);
        Mhi[(size_t)i * FD + col] = (short)h;
        Mlo[(size_t)i * FD + col] = (short)f2bf(m - bf2f(h));
    }
}

// ---------------------------------------------------------------------------
extern "C" void kernel_launch(void* const* d_in, const int* in_sizes, int n_in,
                              void* d_out, int out_size, void* d_ws, size_t ws_size,
                              hipStream_t stream)
{
    const float* x  = (const float*)d_in[0];
    const float* W3 = (const float*)d_in[1];
    const float* b3 = (const float*)d_in[2];
    const float* W6 = (const float*)d_in[3];
    const float* b6 = (const float*)d_in[4];
    const float* W5 = (const float*)d_in[5];
    const float* b5 = (const float*)d_in[6];
    float* out = (float*)d_out;

    char* ws = (char*)d_ws;
    size_t off = 0;
    auto alloc = [&](size_t bytes) -> void* {
        void* p = ws + off;
        off += (bytes + 255) & ~(size_t)255;
        return p;
    };
    float*  s    = (float*)alloc(NR * 4);
    float*  t    = (float*)alloc(NR * 4);
    float*  ts   = (float*)alloc(NR * 4);
    int*    rank = (int*)  alloc(NR * 4);
    float*  p0   = (float*)alloc((size_t)(NCH + 1) * FD * 4);
    float*  p1   = (float*)alloc((size_t)(NCH + 1) * FD * 4);
    short*  W6hi = (short*)alloc(FD * FD * 2);
    short*  W6lo = (short*)alloc(FD * FD * 2);
    short*  W5hi = (short*)alloc(FD * FD * 2);
    short*  W5lo = (short*)alloc(FD * FD * 2);
    short*  xhi  = (short*)alloc((size_t)NR * FD * 2);
    short*  xlo  = (short*)alloc((size_t)NR * FD * 2);
    short*  Mhi  = (short*)alloc((size_t)NR * FD * 2);
    short*  Mlo  = (short*)alloc((size_t)NR * FD * 2);
    float4* scal = (float4*)alloc(NR * 16);
    float*  Gs   = (float*)alloc((size_t)NR * FD * 4);
    (void)ws_size; (void)in_sizes; (void)n_in; (void)out_size;

    k0_prep2<<<dim3(FD * FD / 256, 2), dim3(256), 0, stream>>>(
        W6, W6hi, W6lo, W5, W5hi, W5lo);
    k1_st<<<dim3(NR / 4), dim3(256), 0, stream>>>(x, W3, s, t, rank, xhi, xlo);
    k3a_count<<<dim3(32, 32), dim3(256), 0, stream>>>(t, rank);
    k3b_scatter<<<dim3(NR / 256), dim3(256), 0, stream>>>(t, rank, ts);
    // G = leaky(x@W6^T + b6), rows scattered into sorted-by-t order
    gemm_nt<true, false><<<dim3(FD / 64, NR / 64), dim3(256), 0, stream>>>(
        xhi, xlo, W6hi, W6lo, b6, nullptr, rank, Gs);
    k4a_partial<<<dim3(NCH), dim3(256), 0, stream>>>(Gs, ts, p0, p1);
    k4b_scan<<<dim3(512), dim3(64), 0, stream>>>(p0, p1);
    k5a_pos<<<dim3(NR / 256), dim3(256), 0, stream>>>(s, t, b3, ts, rank, scal);
    k5b_build<<<dim3(NR / 8), dim3(256), 0, stream>>>(scal, ts, Gs, p0, p1, Mhi, Mlo);
    // out = leaky(M@W5^T + b5) + x
    gemm_nt<false, true><<<dim3(FD / 64, NR / 64), dim3(256), 0, stream>>>(
        Mhi, Mlo, W5hi, W5lo, b5, x, nullptr, out);
}

// Round 7
// 158.343 us; speedup vs baseline: 2.4942x; 1.0529x over previous
//
#include <hip/hip_runtime.h>
#include <stdint.h>

#define NR 8192
#define FD 256
#define NCH 1024   // 8-row chunks

typedef __attribute__((ext_vector_type(8))) short bf16x8;
typedef __attribute__((ext_vector_type(4))) float f32x4;

__device__ __forceinline__ float leaky_f(float z){ return z >= 0.0f ? z : 0.1f * z; }

__device__ __forceinline__ unsigned short f2bf(float f){
    union { float f; uint32_t u; } v; v.f = f;
    uint32_t r = v.u + 0x7fffu + ((v.u >> 16) & 1u);
    return (unsigned short)(r >> 16);
}
__device__ __forceinline__ float bf2f(unsigned short h){
    union { uint32_t u; float f; } v; v.u = ((uint32_t)h) << 16;
    return v.f;
}

// ---------------------------------------------------------------------------
// ka_prep (fused k0+k1): blocks [0,512) split W6|W5 into bf16 hi/lo planes;
// blocks [512,2560) compute s,t, split x into planes, zero rank/pos.
__global__ __launch_bounds__(256) void ka_prep(
    const float* __restrict__ x,  const float* __restrict__ W3,
    const float* __restrict__ W6, const float* __restrict__ W5,
    float* __restrict__ s, float* __restrict__ t,
    int* __restrict__ rank, int* __restrict__ pos,
    short* __restrict__ xhi, short* __restrict__ xlo,
    short* __restrict__ W6hi, short* __restrict__ W6lo,
    short* __restrict__ W5hi, short* __restrict__ W5lo)
{
    int b = blockIdx.x;
    int tid = threadIdx.x;
    if (b < 512){
        int i = b * 256 + tid;                 // 0..131071 over two 65536 mats
        bool six = (i < 65536);
        const float* W = six ? W6 : W5;
        short* hi = six ? W6hi : W5hi;
        short* lo = six ? W6lo : W5lo;
        int k = six ? i : i - 65536;
        float v = W[k];
        unsigned short h = f2bf(v);
        hi[k] = (short)h;
        lo[k] = (short)f2bf(v - bf2f(h));
        return;
    }
    int wave = tid >> 6;
    int lane = tid & 63;
    int row  = (b - 512) * 4 + wave;
    const float4* xr = (const float4*)(x + (size_t)row * FD);
    const float4* wa = (const float4*)W3;
    const float4* wb = (const float4*)(W3 + FD);
    float4 xv = xr[lane], av = wa[lane], bv = wb[lane];
    float xe[4] = {xv.x, xv.y, xv.z, xv.w};
    short4 h4, l4;
    short* hp = &h4.x; short* lp = &l4.x;
    #pragma unroll
    for (int e = 0; e < 4; ++e){
        unsigned short h = f2bf(xe[e]);
        hp[e] = (short)h;
        lp[e] = (short)f2bf(xe[e] - bf2f(h));
    }
    *reinterpret_cast<short4*>(xhi + (size_t)row * FD + lane * 4) = h4;
    *reinterpret_cast<short4*>(xlo + (size_t)row * FD + lane * 4) = l4;

    float as = xv.x*av.x + xv.y*av.y + xv.z*av.z + xv.w*av.w;
    float at = xv.x*bv.x + xv.y*bv.y + xv.z*bv.z + xv.w*bv.w;
    #pragma unroll
    for (int off = 32; off > 0; off >>= 1){
        as += __shfl_xor(as, off, 64);
        at += __shfl_xor(at, off, 64);
    }
    if (lane == 0){ s[row] = as; t[row] = at; rank[row] = 0; pos[row] = 0; }
}

// ---------------------------------------------------------------------------
// kb_count (fused k3a + k5a-pos): per 256-segment, count for each j:
//   rank: #{t_r < t_j (tie r<j)}   pos: #{t_r < theta_j}, theta_j=-(s_j+b3).
// pos equals lower_bound(ts,theta) exactly (same multiset, same compares).
__global__ __launch_bounds__(256) void kb_count(const float* __restrict__ t,
                                                const float* __restrict__ s,
                                                const float* __restrict__ b3,
                                                int* __restrict__ rank,
                                                int* __restrict__ pos){
    __shared__ __align__(16) float seg[256];
    int tid = threadIdx.x;
    int j = blockIdx.x * 256 + tid;
    int segBase = blockIdx.y * 256;
    seg[tid] = t[segBase + tid];
    __syncthreads();
    float tj = t[j];
    float theta = -(s[j] + b3[0]);
    int cr = 0, cp = 0;
    #pragma unroll 8
    for (int r = 0; r < 256; r += 4){
        float4 v = *reinterpret_cast<const float4*>(&seg[r]);
        int jp = segBase + r;
        cr += (v.x < tj) || (v.x == tj && (jp + 0) < j);
        cr += (v.y < tj) || (v.y == tj && (jp + 1) < j);
        cr += (v.z < tj) || (v.z == tj && (jp + 2) < j);
        cr += (v.w < tj) || (v.w == tj && (jp + 3) < j);
        cp += (v.x < theta);
        cp += (v.y < theta);
        cp += (v.z < theta);
        cp += (v.w < theta);
    }
    atomicAdd(&rank[j], cr);
    atomicAdd(&pos[j], cp);
}

// ---------------------------------------------------------------------------
// gemm_nt: out[i][n] = leaky( sum_k A[i][k]*Wt[n][k] + bias[n] ) (+ addend)
// Split-bf16 MFMA, pre-split planes. SPLIT-K: 8 waves = 4 row-waves x 2
// K-halves; LDS reduce. 64x64 tile, grid(4,128) -> 2 blk/CU x 8 waves =
// 4 waves/SIMD (2x occupancy vs R3). SCATTER also fuses ts[rank[i]]=t[i].
template<bool SCATTER, bool ADD>
__global__ __launch_bounds__(512, 4) void gemm_nt(
    const short* __restrict__ Ahi, const short* __restrict__ Alo,
    const short* __restrict__ Whi, const short* __restrict__ Wlo,
    const float* __restrict__ bias,
    const float* __restrict__ addend,
    const int* __restrict__ perm,
    const float* __restrict__ tvals,
    float* __restrict__ tsorted,
    float* __restrict__ out)
{
    __shared__ f32x4 red[4][4][64];   // 16 KB
    int tid  = threadIdx.x;
    int wave = tid >> 6;
    int lane = tid & 63;
    int rw = wave & 3;      // row-wave
    int kh = wave >> 2;     // K-half
    int rowBase = blockIdx.y * 64 + rw * 16;
    int colBase = blockIdx.x * 64;

    if (SCATTER && blockIdx.x == 0 && tid < 64){
        int grow = blockIdx.y * 64 + tid;
        tsorted[perm[grow]] = tvals[grow];
    }

    int m16 = lane & 15;
    int k8  = (lane >> 4) * 8;

    f32x4 acc[4];
    #pragma unroll
    for (int c = 0; c < 4; ++c) acc[c] = (f32x4){0.f, 0.f, 0.f, 0.f};

    const short* arh = Ahi + (size_t)(rowBase + m16) * FD + kh * 128 + k8;
    const short* arl = Alo + (size_t)(rowBase + m16) * FD + kh * 128 + k8;

    #pragma unroll
    for (int ks = 0; ks < 4; ++ks){
        int kb = ks * 32;
        bf16x8 ahi = *reinterpret_cast<const bf16x8*>(arh + kb);
        bf16x8 alo = *reinterpret_cast<const bf16x8*>(arl + kb);
        #pragma unroll
        for (int c = 0; c < 4; ++c){
            size_t boff = (size_t)(colBase + c * 16 + m16) * FD + kh * 128 + k8 + kb;
            bf16x8 bhi = *reinterpret_cast<const bf16x8*>(Whi + boff);
            bf16x8 blo = *reinterpret_cast<const bf16x8*>(Wlo + boff);
            acc[c] = __builtin_amdgcn_mfma_f32_16x16x32_bf16(ahi, bhi, acc[c], 0, 0, 0);
            acc[c] = __builtin_amdgcn_mfma_f32_16x16x32_bf16(alo, bhi, acc[c], 0, 0, 0);
            acc[c] = __builtin_amdgcn_mfma_f32_16x16x32_bf16(ahi, blo, acc[c], 0, 0, 0);
        }
    }

    if (kh == 1){
        #pragma unroll
        for (int c = 0; c < 4; ++c) red[rw][c][lane] = acc[c];
    }
    __syncthreads();
    if (kh == 0){
        #pragma unroll
        for (int c = 0; c < 4; ++c){
            f32x4 o = red[rw][c][lane];
            acc[c] = acc[c] + o;
        }
        int rq = (lane >> 4) * 4;
        #pragma unroll
        for (int c = 0; c < 4; ++c){
            int gcol = colBase + c * 16 + m16;
            float bs = bias[gcol];
            #pragma unroll
            for (int j = 0; j < 4; ++j){
                int grow = rowBase + rq + j;
                float v = leaky_f(acc[c][j] + bs);
                if (ADD) v += addend[(size_t)grow * FD + gcol];
                int orow = SCATTER ? perm[grow] : grow;
                out[(size_t)orow * FD + gcol] = v;
            }
        }
    }
}

// ---------------------------------------------------------------------------
// kd_partial: per-chunk (8 rows) column sums of Gs and ts*Gs. Grid 1024.
__global__ __launch_bounds__(256) void kd_partial(const float* __restrict__ Gs,
                                                  const float* __restrict__ ts,
                                                  float* __restrict__ p0,
                                                  float* __restrict__ p1){
    int col = threadIdx.x;
    int chunk = blockIdx.x;
    int base = chunk * 8;
    float s0 = 0.f, s1 = 0.f;
    #pragma unroll
    for (int r = 0; r < 8; ++r){
        float g = Gs[(size_t)(base + r) * FD + col];
        s0 += g;
        s1 += ts[base + r] * g;
    }
    p0[(size_t)chunk * FD + col] = s0;
    p1[(size_t)chunk * FD + col] = s1;
}

// ke_scan: exclusive scan of 1024 chunk-partials per column, in place; grand
// total -> row 1024. Grid 512 single-wave blocks (bid<256 -> p0, else p1).
__global__ __launch_bounds__(64) void ke_scan(float* __restrict__ p0,
                                              float* __restrict__ p1){
    int bid  = blockIdx.x;
    int lane = threadIdx.x;
    float* p = (bid < 256) ? p0 : p1;
    int col = bid & 255;
    int c0 = lane * 16;
    float v[16];
    #pragma unroll
    for (int k = 0; k < 16; ++k) v[k] = p[(size_t)(c0 + k) * FD + col];
    float run = 0.f;
    #pragma unroll
    for (int k = 0; k < 16; ++k) run += v[k];
    float x = run;
    #pragma unroll
    for (int off = 1; off < 64; off <<= 1){
        float n = __shfl_up(x, off, 64);
        if (lane >= off) x += n;
    }
    float e = x - run;
    #pragma unroll
    for (int k = 0; k < 16; ++k){
        p[(size_t)(c0 + k) * FD + col] = e;
        e += v[k];
    }
    if (lane == 63) p[(size_t)NCH * FD + col] = x;  // grand total
}

// ---------------------------------------------------------------------------
// kf_build (k5b with inline scal): M -> bf16 hi/lo planes.
// 4 rows/block, grid 2048 -> 8 blocks/CU for latency hiding.
__global__ __launch_bounds__(256) void kf_build(
    const float* __restrict__ s, const float* __restrict__ t,
    const float* __restrict__ b3,
    const int* __restrict__ rank, const int* __restrict__ pos,
    const float* __restrict__ ts, const float* __restrict__ Gs,
    const float* __restrict__ p0, const float* __restrict__ p1,
    short* __restrict__ Mhi, short* __restrict__ Mlo)
{
    int col = threadIdx.x;
    int i0 = blockIdx.x * 4;
    float T0 = p0[(size_t)NCH * FD + col];
    float T1 = p1[(size_t)NCH * FD + col];
    float c = b3[0];
    const float inv = 1.0f / (float)(NR - 1);
    #pragma unroll
    for (int r = 0; r < 4; ++r){
        int i = i0 + r;
        float sic = s[i] + c;
        float diag = leaky_f(sic + t[i]);
        int ps = pos[i];
        int rk = rank[i];
        int ch = ps >> 3;
        float P0 = p0[(size_t)ch * FD + col];
        float P1 = p1[(size_t)ch * FD + col];
        for (int r2 = ch * 8; r2 < ps; ++r2){   // <=7 iters, uniform
            float g2 = Gs[(size_t)r2 * FD + col];
            P0 += g2;
            P1 += ts[r2] * g2;
        }
        float g = Gs[(size_t)rk * FD + col];
        float full = sic * T0 + T1;
        float act  = sic * (T0 - P0) + (T1 - P1);
        float m = (0.1f * full + 0.9f * act - diag * g) * inv;
        unsigned short h = f2bf(m);
        Mhi[(size_t)i * FD + col] = (short)h;
        Mlo[(size_t)i * FD + col] = (short)f2bf(m - bf2f(h));
    }
}

// ---------------------------------------------------------------------------
extern "C" void kernel_launch(void* const* d_in, const int* in_sizes, int n_in,
                              void* d_out, int out_size, void* d_ws, size_t ws_size,
                              hipStream_t stream)
{
    const float* x  = (const float*)d_in[0];
    const float* W3 = (const float*)d_in[1];
    const float* b3 = (const float*)d_in[2];
    const float* W6 = (const float*)d_in[3];
    const float* b6 = (const float*)d_in[4];
    const float* W5 = (const float*)d_in[5];
    const float* b5 = (const float*)d_in[6];
    float* out = (float*)d_out;

    char* ws = (char*)d_ws;
    size_t off = 0;
    auto alloc = [&](size_t bytes) -> void* {
        void* p = ws + off;
        off += (bytes + 255) & ~(size_t)255;
        return p;
    };
    float*  s    = (float*)alloc(NR * 4);
    float*  t    = (float*)alloc(NR * 4);
    float*  ts   = (float*)alloc(NR * 4);
    int*    rank = (int*)  alloc(NR * 4);
    int*    pos  = (int*)  alloc(NR * 4);
    float*  p0   = (float*)alloc((size_t)(NCH + 1) * FD * 4);
    float*  p1   = (float*)alloc((size_t)(NCH + 1) * FD * 4);
    short*  W6hi = (short*)alloc(FD * FD * 2);
    short*  W6lo = (short*)alloc(FD * FD * 2);
    short*  W5hi = (short*)alloc(FD * FD * 2);
    short*  W5lo = (short*)alloc(FD * FD * 2);
    short*  xhi  = (short*)alloc((size_t)NR * FD * 2);
    short*  xlo  = (short*)alloc((size_t)NR * FD * 2);
    short*  Mhi  = (short*)alloc((size_t)NR * FD * 2);
    short*  Mlo  = (short*)alloc((size_t)NR * FD * 2);
    float*  Gs   = (float*)alloc((size_t)NR * FD * 4);
    (void)ws_size; (void)in_sizes; (void)n_in; (void)out_size;

    // A: weight split + s,t + x planes + rank/pos zero-init
    ka_prep<<<dim3(512 + NR / 4), dim3(256), 0, stream>>>(
        x, W3, W6, W5, s, t, rank, pos, xhi, xlo, W6hi, W6lo, W5hi, W5lo);
    // B: rank + pos counts
    kb_count<<<dim3(32, 32), dim3(256), 0, stream>>>(t, s, b3, rank, pos);
    // C: G = leaky(x@W6^T + b6) scattered to sorted order; fused ts scatter
    gemm_nt<true, false><<<dim3(FD / 64, NR / 64), dim3(512), 0, stream>>>(
        xhi, xlo, W6hi, W6lo, b6, nullptr, rank, t, ts, Gs);
    // D,E: chunk sums + column scan
    kd_partial<<<dim3(NCH), dim3(256), 0, stream>>>(Gs, ts, p0, p1);
    ke_scan<<<dim3(512), dim3(64), 0, stream>>>(p0, p1);
    // F: M (bf16 planes)
    kf_build<<<dim3(NR / 4), dim3(256), 0, stream>>>(
        s, t, b3, rank, pos, ts, Gs, p0, p1, Mhi, Mlo);
    // G: out = leaky(M@W5^T + b5) + x
    gemm_nt<false, true><<<dim3(FD / 64, NR / 64), dim3(512), 0, stream>>>(
        Mhi, Mlo, W5hi, W5lo, b5, x, nullptr, nullptr, nullptr, out);
}